// Round 9
// baseline (472.249 us; speedup 1.0000x reference)
//
#include <hip/hip_runtime.h>
#include <math.h>

#define NUM_TREES 20000
#define MAX_DEPTH 8
#define MAX_SIZE  40
#define VOCAB     30000
#define DIM       128
#define TOT       (MAX_DEPTH * MAX_SIZE)       // 320 tokens per tree
#define NTILE     8
#define TILE_ROWS (VOCAB / NTILE)              // 3750 rows
#define TPA       4                            // trees per block (wave per tree)

typedef unsigned long long ull;

__device__ __forceinline__ double waveSumD(double v) {
    v += __shfl_xor(v, 32);
    v += __shfl_xor(v, 16);
    v += __shfl_xor(v, 8);
    v += __shfl_xor(v, 4);
    v += __shfl_xor(v, 2);
    v += __shfl_xor(v, 1);
    return v;
}

// One packed butterfly for three independent fp64 sums (ILP hides the
// per-step shuffle latency across the three chains).
__device__ __forceinline__ void waveSum3(double& a, double& b, double& c) {
    #pragma unroll
    for (int m = 32; m >= 1; m >>= 1) {
        a += __shfl_xor(a, m);
        b += __shfl_xor(b, m);
        c += __shfl_xor(c, m);
    }
}

// masks may arrive as 1-byte bool or int32; probe word 0 (all-ones input:
// byte layout reads 0x01010101, int32 layout reads 0x00000001).
__device__ __forceinline__ int loadMask(const void* m, size_t idx, bool asByte) {
    return asByte ? (int)((const unsigned char*)m)[idx] : ((const int*)m)[idx];
}

// Phase 0: ts[v] = dot(embedding[v], context_weight) in fp64 (one wave per row)
__global__ __launch_bounds__(256) void tokscore_kernel(
        const float* __restrict__ emb, const float* __restrict__ cw,
        double* __restrict__ ts) {
    int row  = (blockIdx.x * blockDim.x + threadIdx.x) >> 6;
    int lane = threadIdx.x & 63;
    if (row >= VOCAB) return;
    float2 e2 = *(const float2*)(emb + (size_t)row * DIM + lane * 2);
    float2 w2 = *(const float2*)(cw + lane * 2);
    double p = (double)e2.x * (double)w2.x + (double)e2.y * (double)w2.y;
    p = waveSumD(p);
    if (lane == 0) ts[row] = p;
}

// Fused kernel: wave-per-tree fp64 recursion (registers, validated rounds
// 4-8), ballot counting-sort of (coef,tok) pairs into LDS, then half-wave
// float4 gather (lanes 0-31 even rows, 32-63 odd rows; broadcast ds_read_b64
// per half). ROUND 9 CHANGE: __launch_bounds__(256,8) — the (256,4) bound
// was the 53%-occupancy cap (4 blk x 4 waves = 16/32 waves). Kernel used 48
// VGPR, fits the <=64 budget; gather runs 6 loads in flight (peak live ~52
// regs) to stay under the cap without spilling (round-6 spill lesson).
__global__ __launch_bounds__(256, 8) void fused_kernel(
        const int* __restrict__ tokens, const void* __restrict__ masks,
        const double* __restrict__ ts, const float* __restrict__ emb,
        float* __restrict__ out) {
    __shared__ ull l_pair[TPA][TOT];   // 10 KB, tile-sorted pairs per tree

    const int tid  = threadIdx.x;
    const int w    = tid >> 6;          // wave id = local tree index
    const int s    = tid & 63;          // lane = sibling position
    const int tree = blockIdx.x * TPA + w;
    const size_t base = (size_t)tree * TOT;
    const bool mByte = (((const int*)masks)[0] != 1);   // see loadMask comment
    const bool inS = s < MAX_SIZE;

    // ---- per-wave load: tokens/masks/scores into registers.
    int    tok[MAX_DEPTH];
    double e[MAX_DEPTH];
    unsigned int valbit = 0, mskbit = 0;
    #pragma unroll
    for (int d = 0; d < MAX_DEPTH; ++d) {
        int t = -1, m = 0;
        if (inS) {
            t = tokens[base + d * MAX_SIZE + s];
            m = loadMask(masks, base + d * MAX_SIZE + s, mByte);
        }
        tok[d] = t < 0 ? 0 : t;
        e[d]   = inS ? ts[tok[d]] : 0.0;
        if (inS && m != 0) mskbit |= 1u << d;
        if (inS && m != 0 && t >= 0) valbit |= 1u << d;
    }
    unsigned int childbit = 0;
    #pragma unroll
    for (int d = 0; d < MAX_DEPTH - 1; ++d) {
        ull bal = __ballot((mskbit >> (d + 1)) & 1u);
        int nc = (int)__popcll(bal);
        if (nc < 1) nc = 1;
        if (((valbit >> d) & 1u) && s < nc) childbit |= 1u << d;
    }

    // ---- recursion (math identical to validated rounds 4-8; HW f32 exp:
    // rel err ~1e-7, cancels in the softmax ratio).
    double v7 = ((valbit >> 7) & 1u) ? 1.0 : 0.0;
    double pw = waveSumD(e[7] * v7);

    float  attnf[MAX_DEPTH - 1];
    double cArr[MAX_DEPTH - 1];
    #pragma unroll
    for (int d = MAX_DEPTH - 2; d >= 0; --d) {
        float  gf = 1.0f / (1.0f + __expf((float)(-e[d])));
        double cf = ((childbit >> d) & 1u) ? (double)gf : 0.0;  // gate*child
        double a  = fma(cf, pw, e[d]);
        double ex = ((valbit >> d) & 1u) ? (double)__expf((float)a) : 0.0;
        double s0 = ex;            // -> den
        double s1 = ex * cf;       // -> c * den
        double s2 = ex * e[d];     // -> (sum attn*e) * den
        waveSum3(s0, s1, s2);
        double inv = 1.0 / s0;
        double c   = s1 * inv;
        pw = fma(c, pw, s2 * inv);
        attnf[d] = (float)(ex * inv);   // attn
        cArr[d]  = c;
    }
    float coef[MAX_DEPTH];
    double prefix = 1.0;
    #pragma unroll
    for (int d = 0; d <= MAX_DEPTH - 2; ++d) {
        coef[d] = (float)(prefix * (double)attnf[d]);
        prefix *= cArr[d];
    }
    coef[MAX_DEPTH - 1] = (float)(prefix * v7);

    // ---- ballot-based counting sort by vocab tile -> LDS (register-only
    // bookkeeping; all indices compile-time after unroll).
    int tl[MAX_DEPTH];
    unsigned int nzbit = 0;
    #pragma unroll
    for (int d = 0; d < MAX_DEPTH; ++d) {
        tl[d] = tok[d] / TILE_ROWS;
        if (coef[d] != 0.0f) nzbit |= 1u << d;
    }
    const ull ltm = (1ull << s) - 1ull;    // lanes below me

    int cnt[NTILE];
    #pragma unroll
    for (int t = 0; t < NTILE; ++t) cnt[t] = 0;
    #pragma unroll
    for (int d = 0; d < MAX_DEPTH; ++d) {
        bool nz = (nzbit >> d) & 1u;
        #pragma unroll
        for (int t = 0; t < NTILE; ++t)
            cnt[t] += (int)__popcll(__ballot(nz && tl[d] == t));
    }
    int hoff[NTILE + 1];
    hoff[0] = 0;
    #pragma unroll
    for (int t = 0; t < NTILE; ++t) hoff[t + 1] = hoff[t] + cnt[t];

    int ridx[NTILE];
    #pragma unroll
    for (int t = 0; t < NTILE; ++t) ridx[t] = hoff[t];
    #pragma unroll
    for (int d = 0; d < MAX_DEPTH; ++d) {
        bool nz = (nzbit >> d) & 1u;
        int slot = -1;
        #pragma unroll
        for (int t = 0; t < NTILE; ++t) {
            ull m = __ballot(nz && tl[d] == t);
            if (nz && tl[d] == t) slot = ridx[t] + (int)__popcll(m & ltm);
            ridx[t] += (int)__popcll(m);
        }
        if (slot >= 0)
            l_pair[w][slot] =
                ((ull)__float_as_uint(coef[d]) << 32) | (ull)(unsigned)tok[d];
    }
    // nTot is wave-uniform (popcll of ballots); scalarize for loop bounds.
    const int nTot = __builtin_amdgcn_readfirstlane(hoff[NTILE]);

    // ---- gather over the tile-sorted list (wave-local LDS: same wave wrote
    // it; per-wave in-order DS pipeline + compiler lgkmcnt suffices, no
    // barrier — validated rounds 5-8). Each half-wave reads ITS pair via
    // broadcast ds_read_b64 (2 uniform addrs/wave, conflict-free).
    const int hi = (s >= 32) ? 1 : 0;
    const int cb = (s & 31) << 2;          // column base (floats)
    const ull* lp = &l_pair[w][0];
    float a0 = 0.0f, a1 = 0.0f, a2 = 0.0f, a3 = 0.0f;

    int j = 0;
    for (; j + 12 <= nTot; j += 12) {      // 12 rows = 6 dwordx4 in flight
        ull pr[6];
        #pragma unroll
        for (int k = 0; k < 6; ++k) pr[k] = lp[j + 2 * k + hi];
        float4 v[6];
        #pragma unroll
        for (int k = 0; k < 6; ++k)
            v[k] = *(const float4*)(emb + (size_t)(unsigned)pr[k] * DIM + cb);
        #pragma unroll
        for (int k = 0; k < 6; ++k) {
            float wt = __uint_as_float((unsigned)(pr[k] >> 32));
            a0 = fmaf(wt, v[k].x, a0); a1 = fmaf(wt, v[k].y, a1);
            a2 = fmaf(wt, v[k].z, a2); a3 = fmaf(wt, v[k].w, a3);
        }
    }
    for (; j + 2 <= nTot; j += 2) {
        ull pr = lp[j + hi];
        float wt = __uint_as_float((unsigned)(pr >> 32));
        const float4 v = *(const float4*)(emb + (size_t)(unsigned)pr * DIM + cb);
        a0 = fmaf(wt, v.x, a0); a1 = fmaf(wt, v.y, a1);
        a2 = fmaf(wt, v.z, a2); a3 = fmaf(wt, v.w, a3);
    }
    if (j < nTot) {                        // single leftover row: lo half only
        ull pr = lp[j];
        float wt = hi ? 0.0f : __uint_as_float((unsigned)(pr >> 32));
        const float4 v = *(const float4*)(emb + (size_t)(unsigned)pr * DIM + cb);
        a0 = fmaf(wt, v.x, a0); a1 = fmaf(wt, v.y, a1);
        a2 = fmaf(wt, v.z, a2); a3 = fmaf(wt, v.w, a3);
    }

    // Combine half-waves (lane i and i+32 hold the same columns).
    a0 += __shfl_xor(a0, 32);
    a1 += __shfl_xor(a1, 32);
    a2 += __shfl_xor(a2, 32);
    a3 += __shfl_xor(a3, 32);

    if (s < 32) {
        float* op = out + (size_t)tree * DIM + cb;
        *(float4*)op = make_float4(a0, a1, a2, a3);   // single write, no RMW
    }
}

extern "C" void kernel_launch(void* const* d_in, const int* in_sizes, int n_in,
                              void* d_out, int out_size, void* d_ws, size_t ws_size,
                              hipStream_t stream) {
    const int*   tokens = (const int*)d_in[0];
    const void*  masks  = d_in[1];
    const float* emb    = (const float*)d_in[2];
    const float* cw     = (const float*)d_in[3];
    float*       out    = (float*)d_out;
    double*      ts     = (double*)d_ws;   // 30000 doubles = 240 KB scratch

    int ts_blocks = (VOCAB * 64 + 255) / 256;   // one wave per vocab row
    tokscore_kernel<<<ts_blocks, 256, 0, stream>>>(emb, cw, ts);
    fused_kernel<<<NUM_TREES / TPA, 256, 0, stream>>>(tokens, masks, ts, emb, out);
}

// Round 10
// 259.333 us; speedup vs baseline: 1.8210x; 1.8210x over previous
//
#include <hip/hip_runtime.h>
#include <hip/hip_fp16.h>
#include <math.h>

#define NUM_TREES 20000
#define MAX_DEPTH 8
#define MAX_SIZE  40
#define VOCAB     30000
#define DIM       128
#define TOT       (MAX_DEPTH * MAX_SIZE)       // 320 tokens per tree
#define NTILE     8
#define TILE_ROWS (VOCAB / NTILE)              // 3750 rows
#define TPA       4                            // trees per block (wave per tree)

typedef unsigned long long ull;

__device__ __forceinline__ double waveSumD(double v) {
    v += __shfl_xor(v, 32);
    v += __shfl_xor(v, 16);
    v += __shfl_xor(v, 8);
    v += __shfl_xor(v, 4);
    v += __shfl_xor(v, 2);
    v += __shfl_xor(v, 1);
    return v;
}

// One packed butterfly for three independent fp64 sums (ILP hides the
// per-step shuffle latency across the three chains).
__device__ __forceinline__ void waveSum3(double& a, double& b, double& c) {
    #pragma unroll
    for (int m = 32; m >= 1; m >>= 1) {
        a += __shfl_xor(a, m);
        b += __shfl_xor(b, m);
        c += __shfl_xor(c, m);
    }
}

// masks may arrive as 1-byte bool or int32; probe word 0 (all-ones input:
// byte layout reads 0x01010101, int32 layout reads 0x00000001).
__device__ __forceinline__ int loadMask(const void* m, size_t idx, bool asByte) {
    return asByte ? (int)((const unsigned char*)m)[idx] : ((const int*)m)[idx];
}

// Phase 0: ts[v] = dot(embedding[v], context_weight) in fp64 (one wave per row)
__global__ __launch_bounds__(256) void tokscore_kernel(
        const float* __restrict__ emb, const float* __restrict__ cw,
        double* __restrict__ ts) {
    int row  = (blockIdx.x * blockDim.x + threadIdx.x) >> 6;
    int lane = threadIdx.x & 63;
    if (row >= VOCAB) return;
    float2 e2 = *(const float2*)(emb + (size_t)row * DIM + lane * 2);
    float2 w2 = *(const float2*)(cw + lane * 2);
    double p = (double)e2.x * (double)w2.x + (double)e2.y * (double)w2.y;
    p = waveSumD(p);
    if (lane == 0) ts[row] = p;
}

// Convert embedding to fp16 (halves gather traffic: 512B -> 256B per row).
__global__ __launch_bounds__(256) void cvt_kernel(
        const float* __restrict__ emb, __half2* __restrict__ e16) {
    int i = blockIdx.x * 256 + threadIdx.x;     // one float4 per thread
    if (i >= VOCAB * DIM / 4) return;
    float4 f = ((const float4*)emb)[i];
    e16[2 * i + 0] = __floats2half2_rn(f.x, f.y);
    e16[2 * i + 1] = __floats2half2_rn(f.z, f.w);
}

// Shared device body: recursion + sort (validated rounds 4-9).
// Computes l_pair[w][0..nTot) tile-sorted and returns nTot.
__device__ __forceinline__ int recursion_and_sort(
        const int* __restrict__ tokens, const void* __restrict__ masks,
        const double* __restrict__ ts, ull (*l_pair)[TOT],
        int w, int s, size_t base) {
    const bool mByte = (((const int*)masks)[0] != 1);
    const bool inS = s < MAX_SIZE;

    int    tok[MAX_DEPTH];
    double e[MAX_DEPTH];
    unsigned int valbit = 0, mskbit = 0;
    #pragma unroll
    for (int d = 0; d < MAX_DEPTH; ++d) {
        int t = -1, m = 0;
        if (inS) {
            t = tokens[base + d * MAX_SIZE + s];
            m = loadMask(masks, base + d * MAX_SIZE + s, mByte);
        }
        tok[d] = t < 0 ? 0 : t;
        e[d]   = inS ? ts[tok[d]] : 0.0;
        if (inS && m != 0) mskbit |= 1u << d;
        if (inS && m != 0 && t >= 0) valbit |= 1u << d;
    }
    unsigned int childbit = 0;
    #pragma unroll
    for (int d = 0; d < MAX_DEPTH - 1; ++d) {
        ull bal = __ballot((mskbit >> (d + 1)) & 1u);
        int nc = (int)__popcll(bal);
        if (nc < 1) nc = 1;
        if (((valbit >> d) & 1u) && s < nc) childbit |= 1u << d;
    }

    double v7 = ((valbit >> 7) & 1u) ? 1.0 : 0.0;
    double pw = waveSumD(e[7] * v7);

    float  attnf[MAX_DEPTH - 1];
    double cArr[MAX_DEPTH - 1];
    #pragma unroll
    for (int d = MAX_DEPTH - 2; d >= 0; --d) {
        float  gf = 1.0f / (1.0f + __expf((float)(-e[d])));
        double cf = ((childbit >> d) & 1u) ? (double)gf : 0.0;
        double a  = fma(cf, pw, e[d]);
        double ex = ((valbit >> d) & 1u) ? (double)__expf((float)a) : 0.0;
        double s0 = ex, s1 = ex * cf, s2 = ex * e[d];
        waveSum3(s0, s1, s2);
        double inv = 1.0 / s0;
        double c   = s1 * inv;
        pw = fma(c, pw, s2 * inv);
        attnf[d] = (float)(ex * inv);
        cArr[d]  = c;
    }
    float coef[MAX_DEPTH];
    double prefix = 1.0;
    #pragma unroll
    for (int d = 0; d <= MAX_DEPTH - 2; ++d) {
        coef[d] = (float)(prefix * (double)attnf[d]);
        prefix *= cArr[d];
    }
    coef[MAX_DEPTH - 1] = (float)(prefix * v7);

    int tl[MAX_DEPTH];
    unsigned int nzbit = 0;
    #pragma unroll
    for (int d = 0; d < MAX_DEPTH; ++d) {
        tl[d] = tok[d] / TILE_ROWS;
        if (coef[d] != 0.0f) nzbit |= 1u << d;
    }
    const ull ltm = (1ull << s) - 1ull;

    int cnt[NTILE];
    #pragma unroll
    for (int t = 0; t < NTILE; ++t) cnt[t] = 0;
    #pragma unroll
    for (int d = 0; d < MAX_DEPTH; ++d) {
        bool nz = (nzbit >> d) & 1u;
        #pragma unroll
        for (int t = 0; t < NTILE; ++t)
            cnt[t] += (int)__popcll(__ballot(nz && tl[d] == t));
    }
    int hoff[NTILE + 1];
    hoff[0] = 0;
    #pragma unroll
    for (int t = 0; t < NTILE; ++t) hoff[t + 1] = hoff[t] + cnt[t];

    int ridx[NTILE];
    #pragma unroll
    for (int t = 0; t < NTILE; ++t) ridx[t] = hoff[t];
    #pragma unroll
    for (int d = 0; d < MAX_DEPTH; ++d) {
        bool nz = (nzbit >> d) & 1u;
        int slot = -1;
        #pragma unroll
        for (int t = 0; t < NTILE; ++t) {
            ull m = __ballot(nz && tl[d] == t);
            if (nz && tl[d] == t) slot = ridx[t] + (int)__popcll(m & ltm);
            ridx[t] += (int)__popcll(m);
        }
        if (slot >= 0)
            l_pair[w][slot] =
                ((ull)__float_as_uint(coef[d]) << 32) | (ull)(unsigned)tok[d];
    }
    return __builtin_amdgcn_readfirstlane(hoff[NTILE]);
}

// Fused kernel, fp16 gather: half-wave scheme (lanes 0-31 even rows, 32-63
// odd rows), each lane loads uint2 = 4 halves (8B); 32 lanes x 8B = 256B =
// one full fp16 row -> 2 rows per instruction, 8 loads (16 rows) in flight
// at ~48 VGPR. (256,4): validated no-spill config (rounds 6/9: tighter
// bounds spill, +200MB WRITE signature).
__global__ __launch_bounds__(256, 4) void fused16_kernel(
        const int* __restrict__ tokens, const void* __restrict__ masks,
        const double* __restrict__ ts, const __half* __restrict__ e16,
        float* __restrict__ out) {
    __shared__ ull l_pair[TPA][TOT];   // 10 KB, tile-sorted pairs per tree

    const int tid  = threadIdx.x;
    const int w    = tid >> 6;
    const int s    = tid & 63;
    const int tree = blockIdx.x * TPA + w;
    const size_t base = (size_t)tree * TOT;

    const int nTot = recursion_and_sort(tokens, masks, ts, l_pair, w, s, base);

    // Gather (wave-local LDS, no barrier needed — validated rounds 5-9).
    const int hi = (s >= 32) ? 1 : 0;
    const int cb = (s & 31) << 2;          // column base (elements)
    const ull* lp = &l_pair[w][0];
    float a0 = 0.0f, a1 = 0.0f, a2 = 0.0f, a3 = 0.0f;

    int j = 0;
    for (; j + 16 <= nTot; j += 16) {      // 16 rows = 8 uint2 loads in flight
        ull pr[8];
        #pragma unroll
        for (int k = 0; k < 8; ++k) pr[k] = lp[j + 2 * k + hi];
        uint2 v[8];
        #pragma unroll
        for (int k = 0; k < 8; ++k)
            v[k] = *(const uint2*)(e16 + (size_t)(unsigned)pr[k] * DIM + cb);
        #pragma unroll
        for (int k = 0; k < 8; ++k) {
            float wt = __uint_as_float((unsigned)(pr[k] >> 32));
            float2 f0 = __half22float2(*(const __half2*)&v[k].x);
            float2 f1 = __half22float2(*(const __half2*)&v[k].y);
            a0 = fmaf(wt, f0.x, a0); a1 = fmaf(wt, f0.y, a1);
            a2 = fmaf(wt, f1.x, a2); a3 = fmaf(wt, f1.y, a3);
        }
    }
    for (; j + 2 <= nTot; j += 2) {
        ull pr = lp[j + hi];
        float wt = __uint_as_float((unsigned)(pr >> 32));
        uint2 v = *(const uint2*)(e16 + (size_t)(unsigned)pr * DIM + cb);
        float2 f0 = __half22float2(*(const __half2*)&v.x);
        float2 f1 = __half22float2(*(const __half2*)&v.y);
        a0 = fmaf(wt, f0.x, a0); a1 = fmaf(wt, f0.y, a1);
        a2 = fmaf(wt, f1.x, a2); a3 = fmaf(wt, f1.y, a3);
    }
    if (j < nTot) {                        // single leftover row: lo half only
        ull pr = lp[j];
        float wt = hi ? 0.0f : __uint_as_float((unsigned)(pr >> 32));
        uint2 v = *(const uint2*)(e16 + (size_t)(unsigned)pr * DIM + cb);
        float2 f0 = __half22float2(*(const __half2*)&v.x);
        float2 f1 = __half22float2(*(const __half2*)&v.y);
        a0 = fmaf(wt, f0.x, a0); a1 = fmaf(wt, f0.y, a1);
        a2 = fmaf(wt, f1.x, a2); a3 = fmaf(wt, f1.y, a3);
    }

    a0 += __shfl_xor(a0, 32);
    a1 += __shfl_xor(a1, 32);
    a2 += __shfl_xor(a2, 32);
    a3 += __shfl_xor(a3, 32);

    if (s < 32) {
        float* op = out + (size_t)tree * DIM + cb;
        *(float4*)op = make_float4(a0, a1, a2, a3);
    }
}

// Fallback: fp32 fused gather (validated rounds 7-8) for tiny workspaces.
__global__ __launch_bounds__(256, 4) void fused_kernel(
        const int* __restrict__ tokens, const void* __restrict__ masks,
        const double* __restrict__ ts, const float* __restrict__ emb,
        float* __restrict__ out) {
    __shared__ ull l_pair[TPA][TOT];

    const int tid  = threadIdx.x;
    const int w    = tid >> 6;
    const int s    = tid & 63;
    const int tree = blockIdx.x * TPA + w;
    const size_t base = (size_t)tree * TOT;

    const int nTot = recursion_and_sort(tokens, masks, ts, l_pair, w, s, base);

    const int hi = (s >= 32) ? 1 : 0;
    const int cb = (s & 31) << 2;
    const ull* lp = &l_pair[w][0];
    float a0 = 0.0f, a1 = 0.0f, a2 = 0.0f, a3 = 0.0f;

    int j = 0;
    for (; j + 8 <= nTot; j += 8) {
        ull pr[4];
        #pragma unroll
        for (int k = 0; k < 4; ++k) pr[k] = lp[j + 2 * k + hi];
        float4 v[4];
        #pragma unroll
        for (int k = 0; k < 4; ++k)
            v[k] = *(const float4*)(emb + (size_t)(unsigned)pr[k] * DIM + cb);
        #pragma unroll
        for (int k = 0; k < 4; ++k) {
            float wt = __uint_as_float((unsigned)(pr[k] >> 32));
            a0 = fmaf(wt, v[k].x, a0); a1 = fmaf(wt, v[k].y, a1);
            a2 = fmaf(wt, v[k].z, a2); a3 = fmaf(wt, v[k].w, a3);
        }
    }
    for (; j + 2 <= nTot; j += 2) {
        ull pr = lp[j + hi];
        float wt = __uint_as_float((unsigned)(pr >> 32));
        const float4 v = *(const float4*)(emb + (size_t)(unsigned)pr * DIM + cb);
        a0 = fmaf(wt, v.x, a0); a1 = fmaf(wt, v.y, a1);
        a2 = fmaf(wt, v.z, a2); a3 = fmaf(wt, v.w, a3);
    }
    if (j < nTot) {
        ull pr = lp[j];
        float wt = hi ? 0.0f : __uint_as_float((unsigned)(pr >> 32));
        const float4 v = *(const float4*)(emb + (size_t)(unsigned)pr * DIM + cb);
        a0 = fmaf(wt, v.x, a0); a1 = fmaf(wt, v.y, a1);
        a2 = fmaf(wt, v.z, a2); a3 = fmaf(wt, v.w, a3);
    }

    a0 += __shfl_xor(a0, 32);
    a1 += __shfl_xor(a1, 32);
    a2 += __shfl_xor(a2, 32);
    a3 += __shfl_xor(a3, 32);

    if (s < 32) {
        float* op = out + (size_t)tree * DIM + cb;
        *(float4*)op = make_float4(a0, a1, a2, a3);
    }
}

extern "C" void kernel_launch(void* const* d_in, const int* in_sizes, int n_in,
                              void* d_out, int out_size, void* d_ws, size_t ws_size,
                              hipStream_t stream) {
    const int*   tokens = (const int*)d_in[0];
    const void*  masks  = d_in[1];
    const float* emb    = (const float*)d_in[2];
    const float* cw     = (const float*)d_in[3];
    float*       out    = (float*)d_out;

    // Workspace: ts (240 KB) + fp16 embedding table (7.68 MB).
    const size_t o_ts  = 0;
    const size_t o_e16 = o_ts + (size_t)VOCAB * 8;
    const size_t need  = o_e16 + (size_t)VOCAB * DIM * 2;

    double* ts  = (double*)((char*)d_ws + o_ts);
    __half* e16 = (__half*)((char*)d_ws + o_e16);

    int ts_blocks = (VOCAB * 64 + 255) / 256;   // one wave per vocab row
    tokscore_kernel<<<ts_blocks, 256, 0, stream>>>(emb, cw, ts);

    if (ws_size >= need) {
        int cvt_blocks = (VOCAB * DIM / 4 + 255) / 256;
        cvt_kernel<<<cvt_blocks, 256, 0, stream>>>(emb, (__half2*)e16);
        fused16_kernel<<<NUM_TREES / TPA, 256, 0, stream>>>(tokens, masks, ts,
                                                            e16, out);
    } else {
        fused_kernel<<<NUM_TREES / TPA, 256, 0, stream>>>(tokens, masks, ts,
                                                          emb, out);
    }
}

// Round 11
// 240.964 us; speedup vs baseline: 1.9598x; 1.0762x over previous
//
#include <hip/hip_runtime.h>
#include <hip/hip_fp16.h>
#include <math.h>

#define NUM_TREES 20000
#define MAX_DEPTH 8
#define MAX_SIZE  40
#define VOCAB     30000
#define DIM       128
#define TOT       (MAX_DEPTH * MAX_SIZE)       // 320 tokens per tree
#define NTILE     8
#define TILE_ROWS (VOCAB / NTILE)              // 3750 rows
#define TPA       4                            // trees per block (wave per tree)

typedef unsigned long long ull;

__device__ __forceinline__ double waveSumD(double v) {
    v += __shfl_xor(v, 32);
    v += __shfl_xor(v, 16);
    v += __shfl_xor(v, 8);
    v += __shfl_xor(v, 4);
    v += __shfl_xor(v, 2);
    v += __shfl_xor(v, 1);
    return v;
}

// One packed butterfly for three independent fp64 sums (ILP hides the
// per-step shuffle latency across the three chains).
__device__ __forceinline__ void waveSum3(double& a, double& b, double& c) {
    #pragma unroll
    for (int m = 32; m >= 1; m >>= 1) {
        a += __shfl_xor(a, m);
        b += __shfl_xor(b, m);
        c += __shfl_xor(c, m);
    }
}

// masks may arrive as 1-byte bool or int32; probe word 0 (all-ones input:
// byte layout reads 0x01010101, int32 layout reads 0x00000001).
__device__ __forceinline__ int loadMask(const void* m, size_t idx, bool asByte) {
    return asByte ? (int)((const unsigned char*)m)[idx] : ((const int*)m)[idx];
}

// Phase 0: ts[v] = dot(embedding[v], context_weight) in fp64 (one wave per row)
__global__ __launch_bounds__(256) void tokscore_kernel(
        const float* __restrict__ emb, const float* __restrict__ cw,
        double* __restrict__ ts) {
    int row  = (blockIdx.x * blockDim.x + threadIdx.x) >> 6;
    int lane = threadIdx.x & 63;
    if (row >= VOCAB) return;
    float2 e2 = *(const float2*)(emb + (size_t)row * DIM + lane * 2);
    float2 w2 = *(const float2*)(cw + lane * 2);
    double p = (double)e2.x * (double)w2.x + (double)e2.y * (double)w2.y;
    p = waveSumD(p);
    if (lane == 0) ts[row] = p;
}

// Convert embedding to fp16 (halves gather traffic: 512B -> 256B per row).
__global__ __launch_bounds__(256) void cvt_kernel(
        const float* __restrict__ emb, __half2* __restrict__ e16) {
    int i = blockIdx.x * 256 + threadIdx.x;     // one float4 per thread
    if (i >= VOCAB * DIM / 4) return;
    float4 f = ((const float4*)emb)[i];
    e16[2 * i + 0] = __floats2half2_rn(f.x, f.y);
    e16[2 * i + 1] = __floats2half2_rn(f.z, f.w);
}

// Shared device body: recursion + sort (validated rounds 4-10).
// Computes l_pair[w][0..nTot) tile-sorted and returns nTot.
__device__ __forceinline__ int recursion_and_sort(
        const int* __restrict__ tokens, const void* __restrict__ masks,
        const double* __restrict__ ts, ull (*l_pair)[TOT],
        int w, int s, size_t base) {
    const bool mByte = (((const int*)masks)[0] != 1);
    const bool inS = s < MAX_SIZE;

    int    tok[MAX_DEPTH];
    double e[MAX_DEPTH];
    unsigned int valbit = 0, mskbit = 0;
    #pragma unroll
    for (int d = 0; d < MAX_DEPTH; ++d) {
        int t = -1, m = 0;
        if (inS) {
            t = tokens[base + d * MAX_SIZE + s];
            m = loadMask(masks, base + d * MAX_SIZE + s, mByte);
        }
        tok[d] = t < 0 ? 0 : t;
        e[d]   = inS ? ts[tok[d]] : 0.0;
        if (inS && m != 0) mskbit |= 1u << d;
        if (inS && m != 0 && t >= 0) valbit |= 1u << d;
    }
    unsigned int childbit = 0;
    #pragma unroll
    for (int d = 0; d < MAX_DEPTH - 1; ++d) {
        ull bal = __ballot((mskbit >> (d + 1)) & 1u);
        int nc = (int)__popcll(bal);
        if (nc < 1) nc = 1;
        if (((valbit >> d) & 1u) && s < nc) childbit |= 1u << d;
    }

    double v7 = ((valbit >> 7) & 1u) ? 1.0 : 0.0;
    double pw = waveSumD(e[7] * v7);

    float  attnf[MAX_DEPTH - 1];
    double cArr[MAX_DEPTH - 1];
    #pragma unroll
    for (int d = MAX_DEPTH - 2; d >= 0; --d) {
        float  gf = 1.0f / (1.0f + __expf((float)(-e[d])));
        double cf = ((childbit >> d) & 1u) ? (double)gf : 0.0;
        double a  = fma(cf, pw, e[d]);
        double ex = ((valbit >> d) & 1u) ? (double)__expf((float)a) : 0.0;
        double s0 = ex, s1 = ex * cf, s2 = ex * e[d];
        waveSum3(s0, s1, s2);
        double inv = 1.0 / s0;
        double c   = s1 * inv;
        pw = fma(c, pw, s2 * inv);
        attnf[d] = (float)(ex * inv);
        cArr[d]  = c;
    }
    float coef[MAX_DEPTH];
    double prefix = 1.0;
    #pragma unroll
    for (int d = 0; d <= MAX_DEPTH - 2; ++d) {
        coef[d] = (float)(prefix * (double)attnf[d]);
        prefix *= cArr[d];
    }
    coef[MAX_DEPTH - 1] = (float)(prefix * v7);

    int tl[MAX_DEPTH];
    unsigned int nzbit = 0;
    #pragma unroll
    for (int d = 0; d < MAX_DEPTH; ++d) {
        tl[d] = tok[d] / TILE_ROWS;
        if (coef[d] != 0.0f) nzbit |= 1u << d;
    }
    const ull ltm = (1ull << s) - 1ull;

    int cnt[NTILE];
    #pragma unroll
    for (int t = 0; t < NTILE; ++t) cnt[t] = 0;
    #pragma unroll
    for (int d = 0; d < MAX_DEPTH; ++d) {
        bool nz = (nzbit >> d) & 1u;
        #pragma unroll
        for (int t = 0; t < NTILE; ++t)
            cnt[t] += (int)__popcll(__ballot(nz && tl[d] == t));
    }
    int hoff[NTILE + 1];
    hoff[0] = 0;
    #pragma unroll
    for (int t = 0; t < NTILE; ++t) hoff[t + 1] = hoff[t] + cnt[t];

    int ridx[NTILE];
    #pragma unroll
    for (int t = 0; t < NTILE; ++t) ridx[t] = hoff[t];
    #pragma unroll
    for (int d = 0; d < MAX_DEPTH; ++d) {
        bool nz = (nzbit >> d) & 1u;
        int slot = -1;
        #pragma unroll
        for (int t = 0; t < NTILE; ++t) {
            ull m = __ballot(nz && tl[d] == t);
            if (nz && tl[d] == t) slot = ridx[t] + (int)__popcll(m & ltm);
            ridx[t] += (int)__popcll(m);
        }
        if (slot >= 0)
            l_pair[w][slot] =
                ((ull)__float_as_uint(coef[d]) << 32) | (ull)(unsigned)tok[d];
    }
    return __builtin_amdgcn_readfirstlane(hoff[NTILE]);
}

// Fused kernel, fp16 quarter-wave gather: lanes 0-15 row j, 16-31 j+1,
// 32-47 j+2, 48-63 j+3; each lane loads uint4 = 8 halves (16B); 64 lanes x
// 16B = 1KB = FOUR fp16 rows per instruction. 8 loads in flight = 32 rows =
// 8KB/wave (2x round 10's in-flight bytes). sched_barrier(0) pins all 8
// loads before any consume (rounds 8/9: scheduler otherwise recycles regs
// and serializes). Peak live ~75 VGPR — legal at the (256,4) cap of 128.
// (256,4): validated no-spill config (rounds 6/9: tighter bounds spill).
__global__ __launch_bounds__(256, 4) void fused16_kernel(
        const int* __restrict__ tokens, const void* __restrict__ masks,
        const double* __restrict__ ts, const __half* __restrict__ e16,
        float* __restrict__ out) {
    __shared__ ull l_pair[TPA][TOT];   // 10 KB, tile-sorted pairs per tree

    const int tid  = threadIdx.x;
    const int w    = tid >> 6;
    const int s    = tid & 63;
    const int tree = blockIdx.x * TPA + w;
    const size_t base = (size_t)tree * TOT;

    const int nTot = recursion_and_sort(tokens, masks, ts, l_pair, w, s, base);

    // Gather (wave-local LDS, no barrier needed — validated rounds 5-10).
    const int q  = s >> 4;                 // quarter id: row offset 0..3
    const int cb = (s & 15) << 3;          // column base: 8 elements per lane
    const ull* lp = &l_pair[w][0];
    float a0 = 0.f, a1 = 0.f, a2 = 0.f, a3 = 0.f;
    float a4 = 0.f, a5 = 0.f, a6 = 0.f, a7 = 0.f;

    int j = 0;
    for (; j + 32 <= nTot; j += 32) {      // 32 rows = 8 uint4 loads in flight
        ull pr[8];
        #pragma unroll
        for (int k = 0; k < 8; ++k) pr[k] = lp[j + 4 * k + q];
        uint4 v[8];
        #pragma unroll
        for (int k = 0; k < 8; ++k)
            v[k] = *(const uint4*)(e16 + (size_t)(unsigned)pr[k] * DIM + cb);
        __builtin_amdgcn_sched_barrier(0);  // all 8 loads issued before use
        #pragma unroll
        for (int k = 0; k < 8; ++k) {
            float wt = __uint_as_float((unsigned)(pr[k] >> 32));
            float2 f0 = __half22float2(*(const __half2*)&v[k].x);
            float2 f1 = __half22float2(*(const __half2*)&v[k].y);
            float2 f2 = __half22float2(*(const __half2*)&v[k].z);
            float2 f3 = __half22float2(*(const __half2*)&v[k].w);
            a0 = fmaf(wt, f0.x, a0); a1 = fmaf(wt, f0.y, a1);
            a2 = fmaf(wt, f1.x, a2); a3 = fmaf(wt, f1.y, a3);
            a4 = fmaf(wt, f2.x, a4); a5 = fmaf(wt, f2.y, a5);
            a6 = fmaf(wt, f3.x, a6); a7 = fmaf(wt, f3.y, a7);
        }
    }
    for (; j + 4 <= nTot; j += 4) {        // 4 rows per step
        ull pr = lp[j + q];
        float wt = __uint_as_float((unsigned)(pr >> 32));
        uint4 v = *(const uint4*)(e16 + (size_t)(unsigned)pr * DIM + cb);
        float2 f0 = __half22float2(*(const __half2*)&v.x);
        float2 f1 = __half22float2(*(const __half2*)&v.y);
        float2 f2 = __half22float2(*(const __half2*)&v.z);
        float2 f3 = __half22float2(*(const __half2*)&v.w);
        a0 = fmaf(wt, f0.x, a0); a1 = fmaf(wt, f0.y, a1);
        a2 = fmaf(wt, f1.x, a2); a3 = fmaf(wt, f1.y, a3);
        a4 = fmaf(wt, f2.x, a4); a5 = fmaf(wt, f2.y, a5);
        a6 = fmaf(wt, f3.x, a6); a7 = fmaf(wt, f3.y, a7);
    }
    if (j < nTot) {                        // 1-3 leftover rows
        int rem = nTot - j;
        ull pr = lp[j + (q < rem ? q : 0)];            // inactive quarters re-
        float wt = (q < rem) ? __uint_as_float((unsigned)(pr >> 32)) : 0.0f;
        uint4 v = *(const uint4*)(e16 + (size_t)(unsigned)pr * DIM + cb);
        float2 f0 = __half22float2(*(const __half2*)&v.x); // read row j, wt=0
        float2 f1 = __half22float2(*(const __half2*)&v.y);
        float2 f2 = __half22float2(*(const __half2*)&v.z);
        float2 f3 = __half22float2(*(const __half2*)&v.w);
        a0 = fmaf(wt, f0.x, a0); a1 = fmaf(wt, f0.y, a1);
        a2 = fmaf(wt, f1.x, a2); a3 = fmaf(wt, f1.y, a3);
        a4 = fmaf(wt, f2.x, a4); a5 = fmaf(wt, f2.y, a5);
        a6 = fmaf(wt, f3.x, a6); a7 = fmaf(wt, f3.y, a7);
    }

    // Reduce across the 4 quarters (lanes with equal (s&15) share columns).
    a0 += __shfl_xor(a0, 16); a1 += __shfl_xor(a1, 16);
    a2 += __shfl_xor(a2, 16); a3 += __shfl_xor(a3, 16);
    a4 += __shfl_xor(a4, 16); a5 += __shfl_xor(a5, 16);
    a6 += __shfl_xor(a6, 16); a7 += __shfl_xor(a7, 16);
    a0 += __shfl_xor(a0, 32); a1 += __shfl_xor(a1, 32);
    a2 += __shfl_xor(a2, 32); a3 += __shfl_xor(a3, 32);
    a4 += __shfl_xor(a4, 32); a5 += __shfl_xor(a5, 32);
    a6 += __shfl_xor(a6, 32); a7 += __shfl_xor(a7, 32);

    if (s < 16) {
        float* op = out + (size_t)tree * DIM + cb;
        *(float4*)op       = make_float4(a0, a1, a2, a3);
        *(float4*)(op + 4) = make_float4(a4, a5, a6, a7);
    }
}

// Fallback: fp32 fused gather (validated rounds 7-8) for tiny workspaces.
__global__ __launch_bounds__(256, 4) void fused_kernel(
        const int* __restrict__ tokens, const void* __restrict__ masks,
        const double* __restrict__ ts, const float* __restrict__ emb,
        float* __restrict__ out) {
    __shared__ ull l_pair[TPA][TOT];

    const int tid  = threadIdx.x;
    const int w    = tid >> 6;
    const int s    = tid & 63;
    const int tree = blockIdx.x * TPA + w;
    const size_t base = (size_t)tree * TOT;

    const int nTot = recursion_and_sort(tokens, masks, ts, l_pair, w, s, base);

    const int hi = (s >= 32) ? 1 : 0;
    const int cb = (s & 31) << 2;
    const ull* lp = &l_pair[w][0];
    float a0 = 0.0f, a1 = 0.0f, a2 = 0.0f, a3 = 0.0f;

    int j = 0;
    for (; j + 8 <= nTot; j += 8) {
        ull pr[4];
        #pragma unroll
        for (int k = 0; k < 4; ++k) pr[k] = lp[j + 2 * k + hi];
        float4 v[4];
        #pragma unroll
        for (int k = 0; k < 4; ++k)
            v[k] = *(const float4*)(emb + (size_t)(unsigned)pr[k] * DIM + cb);
        #pragma unroll
        for (int k = 0; k < 4; ++k) {
            float wt = __uint_as_float((unsigned)(pr[k] >> 32));
            a0 = fmaf(wt, v[k].x, a0); a1 = fmaf(wt, v[k].y, a1);
            a2 = fmaf(wt, v[k].z, a2); a3 = fmaf(wt, v[k].w, a3);
        }
    }
    for (; j + 2 <= nTot; j += 2) {
        ull pr = lp[j + hi];
        float wt = __uint_as_float((unsigned)(pr >> 32));
        const float4 v = *(const float4*)(emb + (size_t)(unsigned)pr * DIM + cb);
        a0 = fmaf(wt, v.x, a0); a1 = fmaf(wt, v.y, a1);
        a2 = fmaf(wt, v.z, a2); a3 = fmaf(wt, v.w, a3);
    }
    if (j < nTot) {
        ull pr = lp[j];
        float wt = hi ? 0.0f : __uint_as_float((unsigned)(pr >> 32));
        const float4 v = *(const float4*)(emb + (size_t)(unsigned)pr * DIM + cb);
        a0 = fmaf(wt, v.x, a0); a1 = fmaf(wt, v.y, a1);
        a2 = fmaf(wt, v.z, a2); a3 = fmaf(wt, v.w, a3);
    }

    a0 += __shfl_xor(a0, 32);
    a1 += __shfl_xor(a1, 32);
    a2 += __shfl_xor(a2, 32);
    a3 += __shfl_xor(a3, 32);

    if (s < 32) {
        float* op = out + (size_t)tree * DIM + cb;
        *(float4*)op = make_float4(a0, a1, a2, a3);
    }
}

extern "C" void kernel_launch(void* const* d_in, const int* in_sizes, int n_in,
                              void* d_out, int out_size, void* d_ws, size_t ws_size,
                              hipStream_t stream) {
    const int*   tokens = (const int*)d_in[0];
    const void*  masks  = d_in[1];
    const float* emb    = (const float*)d_in[2];
    const float* cw     = (const float*)d_in[3];
    float*       out    = (float*)d_out;

    // Workspace: ts (240 KB) + fp16 embedding table (7.68 MB).
    const size_t o_ts  = 0;
    const size_t o_e16 = o_ts + (size_t)VOCAB * 8;
    const size_t need  = o_e16 + (size_t)VOCAB * DIM * 2;

    double* ts  = (double*)((char*)d_ws + o_ts);
    __half* e16 = (__half*)((char*)d_ws + o_e16);

    int ts_blocks = (VOCAB * 64 + 255) / 256;   // one wave per vocab row
    tokscore_kernel<<<ts_blocks, 256, 0, stream>>>(emb, cw, ts);

    if (ws_size >= need) {
        int cvt_blocks = (VOCAB * DIM / 4 + 255) / 256;
        cvt_kernel<<<cvt_blocks, 256, 0, stream>>>(emb, (__half2*)e16);
        fused16_kernel<<<NUM_TREES / TPA, 256, 0, stream>>>(tokens, masks, ts,
                                                            e16, out);
    } else {
        fused_kernel<<<NUM_TREES / TPA, 256, 0, stream>>>(tokens, masks, ts,
                                                          emb, out);
    }
}

// Round 12
// 233.454 us; speedup vs baseline: 2.0229x; 1.0322x over previous
//
#include <hip/hip_runtime.h>
#include <hip/hip_fp16.h>
#include <math.h>

#define NUM_TREES 20000
#define MAX_DEPTH 8
#define MAX_SIZE  40
#define VOCAB     30000
#define DIM       128
#define TOT       (MAX_DEPTH * MAX_SIZE)       // 320 tokens per tree
#define NTILE     8
#define TILE_ROWS (VOCAB / NTILE)              // 3750 rows
#define TPA       4                            // trees per block (wave per tree)

typedef unsigned long long ull;

__device__ __forceinline__ double waveSumD(double v) {
    v += __shfl_xor(v, 32);
    v += __shfl_xor(v, 16);
    v += __shfl_xor(v, 8);
    v += __shfl_xor(v, 4);
    v += __shfl_xor(v, 2);
    v += __shfl_xor(v, 1);
    return v;
}

__device__ __forceinline__ float waveSumF(float v) {
    v += __shfl_xor(v, 32);
    v += __shfl_xor(v, 16);
    v += __shfl_xor(v, 8);
    v += __shfl_xor(v, 4);
    v += __shfl_xor(v, 2);
    v += __shfl_xor(v, 1);
    return v;
}

// One packed butterfly for three independent fp32 sums (ILP hides the
// per-step shuffle latency across the three chains).
__device__ __forceinline__ void waveSum3F(float& a, float& b, float& c) {
    #pragma unroll
    for (int m = 32; m >= 1; m >>= 1) {
        a += __shfl_xor(a, m);
        b += __shfl_xor(b, m);
        c += __shfl_xor(c, m);
    }
}

// masks may arrive as 1-byte bool or int32; probe word 0 (all-ones input:
// byte layout reads 0x01010101, int32 layout reads 0x00000001).
__device__ __forceinline__ int loadMask(const void* m, size_t idx, bool asByte) {
    return asByte ? (int)((const unsigned char*)m)[idx] : ((const int*)m)[idx];
}

// Phase 0 (fused): ts[v] = dot(embedding[v], cw) (fp64 reduce, f32 store)
// AND fp16 conversion of the row the wave already holds — kills the separate
// cvt kernel and its 15 MB re-read.
__global__ __launch_bounds__(256) void tokscore_kernel(
        const float* __restrict__ emb, const float* __restrict__ cw,
        float* __restrict__ ts, __half2* __restrict__ e16) {
    int row  = (blockIdx.x * blockDim.x + threadIdx.x) >> 6;
    int lane = threadIdx.x & 63;
    if (row >= VOCAB) return;
    float2 e2 = *(const float2*)(emb + (size_t)row * DIM + lane * 2);
    float2 w2 = *(const float2*)(cw + lane * 2);
    if (e16) e16[(size_t)row * 64 + lane] = __floats2half2_rn(e2.x, e2.y);
    double p = (double)e2.x * (double)w2.x + (double)e2.y * (double)w2.y;
    p = waveSumD(p);
    if (lane == 0) ts[row] = (float)p;
}

// Shared device body: fp32 recursion + ballot sort (structure validated
// rounds 4-11; fp32 this round — reference itself is jax fp32; range check:
// |e|<=3, pw<=24, exp(24)=2.6e10, den<=1e12 all in f32 range; coef rel err
// ~1e-6 -> output ~1e-5, two orders under the fp16-table absmax 0.0078).
__device__ __forceinline__ int recursion_and_sort(
        const int* __restrict__ tokens, const void* __restrict__ masks,
        const float* __restrict__ ts, ull (*l_pair)[TOT],
        int w, int s, size_t base) {
    const bool mByte = (((const int*)masks)[0] != 1);
    const bool inS = s < MAX_SIZE;

    int   tok[MAX_DEPTH];
    float e[MAX_DEPTH];
    unsigned int valbit = 0, mskbit = 0;
    #pragma unroll
    for (int d = 0; d < MAX_DEPTH; ++d) {
        int t = -1, m = 0;
        if (inS) {
            t = tokens[base + d * MAX_SIZE + s];
            m = loadMask(masks, base + d * MAX_SIZE + s, mByte);
        }
        tok[d] = t < 0 ? 0 : t;
        e[d]   = inS ? ts[tok[d]] : 0.0f;
        if (inS && m != 0) mskbit |= 1u << d;
        if (inS && m != 0 && t >= 0) valbit |= 1u << d;
    }
    unsigned int childbit = 0;
    #pragma unroll
    for (int d = 0; d < MAX_DEPTH - 1; ++d) {
        ull bal = __ballot((mskbit >> (d + 1)) & 1u);
        int nc = (int)__popcll(bal);
        if (nc < 1) nc = 1;
        if (((valbit >> d) & 1u) && s < nc) childbit |= 1u << d;
    }

    float v7 = ((valbit >> 7) & 1u) ? 1.0f : 0.0f;
    float pw = waveSumF(e[7] * v7);

    float attnf[MAX_DEPTH - 1];
    float cArr[MAX_DEPTH - 1];
    #pragma unroll
    for (int d = MAX_DEPTH - 2; d >= 0; --d) {
        float gf = 1.0f / (1.0f + __expf(-e[d]));
        float cf = ((childbit >> d) & 1u) ? gf : 0.0f;   // gate*child
        float a  = fmaf(cf, pw, e[d]);
        float ex = ((valbit >> d) & 1u) ? __expf(a) : 0.0f;
        float s0 = ex;            // -> den
        float s1 = ex * cf;       // -> c * den
        float s2 = ex * e[d];     // -> (sum attn*e) * den
        waveSum3F(s0, s1, s2);
        float inv = 1.0f / s0;
        float c   = s1 * inv;
        pw = fmaf(c, pw, s2 * inv);
        attnf[d] = ex * inv;      // attn
        cArr[d]  = c;
    }
    float coef[MAX_DEPTH];
    float prefix = 1.0f;
    #pragma unroll
    for (int d = 0; d <= MAX_DEPTH - 2; ++d) {
        coef[d] = prefix * attnf[d];
        prefix *= cArr[d];
    }
    coef[MAX_DEPTH - 1] = prefix * v7;

    int tl[MAX_DEPTH];
    unsigned int nzbit = 0;
    #pragma unroll
    for (int d = 0; d < MAX_DEPTH; ++d) {
        tl[d] = tok[d] / TILE_ROWS;
        if (coef[d] != 0.0f) nzbit |= 1u << d;
    }
    const ull ltm = (1ull << s) - 1ull;

    int cnt[NTILE];
    #pragma unroll
    for (int t = 0; t < NTILE; ++t) cnt[t] = 0;
    #pragma unroll
    for (int d = 0; d < MAX_DEPTH; ++d) {
        bool nz = (nzbit >> d) & 1u;
        #pragma unroll
        for (int t = 0; t < NTILE; ++t)
            cnt[t] += (int)__popcll(__ballot(nz && tl[d] == t));
    }
    int hoff[NTILE + 1];
    hoff[0] = 0;
    #pragma unroll
    for (int t = 0; t < NTILE; ++t) hoff[t + 1] = hoff[t] + cnt[t];

    int ridx[NTILE];
    #pragma unroll
    for (int t = 0; t < NTILE; ++t) ridx[t] = hoff[t];
    #pragma unroll
    for (int d = 0; d < MAX_DEPTH; ++d) {
        bool nz = (nzbit >> d) & 1u;
        int slot = -1;
        #pragma unroll
        for (int t = 0; t < NTILE; ++t) {
            ull m = __ballot(nz && tl[d] == t);
            if (nz && tl[d] == t) slot = ridx[t] + (int)__popcll(m & ltm);
            ridx[t] += (int)__popcll(m);
        }
        if (slot >= 0)
            l_pair[w][slot] =
                ((ull)__float_as_uint(coef[d]) << 32) | (ull)(unsigned)tok[d];
    }
    return __builtin_amdgcn_readfirstlane(hoff[NTILE]);
}

// Fused kernel, fp16 quarter-wave gather (validated round 11): lanes 0-15
// row j, 16-31 j+1, 32-47 j+2, 48-63 j+3; each lane loads uint4 = 8 halves;
// 64 lanes x 16B = 1KB = FOUR fp16 rows per instruction; 8 loads in flight.
// sched_barrier(0) pins all 8 loads before any consume.
// (256,4): validated no-spill config (rounds 6/9: tighter bounds spill).
__global__ __launch_bounds__(256, 4) void fused16_kernel(
        const int* __restrict__ tokens, const void* __restrict__ masks,
        const float* __restrict__ ts, const __half* __restrict__ e16,
        float* __restrict__ out) {
    __shared__ ull l_pair[TPA][TOT];   // 10 KB, tile-sorted pairs per tree

    const int tid  = threadIdx.x;
    const int w    = tid >> 6;
    const int s    = tid & 63;
    const int tree = blockIdx.x * TPA + w;
    const size_t base = (size_t)tree * TOT;

    const int nTot = recursion_and_sort(tokens, masks, ts, l_pair, w, s, base);

    // Gather (wave-local LDS, no barrier needed — validated rounds 5-11).
    const int q  = s >> 4;                 // quarter id: row offset 0..3
    const int cb = (s & 15) << 3;          // column base: 8 elements per lane
    const ull* lp = &l_pair[w][0];
    float a0 = 0.f, a1 = 0.f, a2 = 0.f, a3 = 0.f;
    float a4 = 0.f, a5 = 0.f, a6 = 0.f, a7 = 0.f;

    int j = 0;
    for (; j + 32 <= nTot; j += 32) {      // 32 rows = 8 uint4 loads in flight
        ull pr[8];
        #pragma unroll
        for (int k = 0; k < 8; ++k) pr[k] = lp[j + 4 * k + q];
        uint4 v[8];
        #pragma unroll
        for (int k = 0; k < 8; ++k)
            v[k] = *(const uint4*)(e16 + (size_t)(unsigned)pr[k] * DIM + cb);
        __builtin_amdgcn_sched_barrier(0);  // all 8 loads issued before use
        #pragma unroll
        for (int k = 0; k < 8; ++k) {
            float wt = __uint_as_float((unsigned)(pr[k] >> 32));
            float2 f0 = __half22float2(*(const __half2*)&v[k].x);
            float2 f1 = __half22float2(*(const __half2*)&v[k].y);
            float2 f2 = __half22float2(*(const __half2*)&v[k].z);
            float2 f3 = __half22float2(*(const __half2*)&v[k].w);
            a0 = fmaf(wt, f0.x, a0); a1 = fmaf(wt, f0.y, a1);
            a2 = fmaf(wt, f1.x, a2); a3 = fmaf(wt, f1.y, a3);
            a4 = fmaf(wt, f2.x, a4); a5 = fmaf(wt, f2.y, a5);
            a6 = fmaf(wt, f3.x, a6); a7 = fmaf(wt, f3.y, a7);
        }
    }
    for (; j + 4 <= nTot; j += 4) {        // 4 rows per step
        ull pr = lp[j + q];
        float wt = __uint_as_float((unsigned)(pr >> 32));
        uint4 v = *(const uint4*)(e16 + (size_t)(unsigned)pr * DIM + cb);
        float2 f0 = __half22float2(*(const __half2*)&v.x);
        float2 f1 = __half22float2(*(const __half2*)&v.y);
        float2 f2 = __half22float2(*(const __half2*)&v.z);
        float2 f3 = __half22float2(*(const __half2*)&v.w);
        a0 = fmaf(wt, f0.x, a0); a1 = fmaf(wt, f0.y, a1);
        a2 = fmaf(wt, f1.x, a2); a3 = fmaf(wt, f1.y, a3);
        a4 = fmaf(wt, f2.x, a4); a5 = fmaf(wt, f2.y, a5);
        a6 = fmaf(wt, f3.x, a6); a7 = fmaf(wt, f3.y, a7);
    }
    if (j < nTot) {                        // 1-3 leftover rows
        int rem = nTot - j;
        ull pr = lp[j + (q < rem ? q : 0)];            // inactive quarters re-
        float wt = (q < rem) ? __uint_as_float((unsigned)(pr >> 32)) : 0.0f;
        uint4 v = *(const uint4*)(e16 + (size_t)(unsigned)pr * DIM + cb);
        float2 f0 = __half22float2(*(const __half2*)&v.x); // read row j, wt=0
        float2 f1 = __half22float2(*(const __half2*)&v.y);
        float2 f2 = __half22float2(*(const __half2*)&v.z);
        float2 f3 = __half22float2(*(const __half2*)&v.w);
        a0 = fmaf(wt, f0.x, a0); a1 = fmaf(wt, f0.y, a1);
        a2 = fmaf(wt, f1.x, a2); a3 = fmaf(wt, f1.y, a3);
        a4 = fmaf(wt, f2.x, a4); a5 = fmaf(wt, f2.y, a5);
        a6 = fmaf(wt, f3.x, a6); a7 = fmaf(wt, f3.y, a7);
    }

    // Reduce across the 4 quarters (lanes with equal (s&15) share columns).
    a0 += __shfl_xor(a0, 16); a1 += __shfl_xor(a1, 16);
    a2 += __shfl_xor(a2, 16); a3 += __shfl_xor(a3, 16);
    a4 += __shfl_xor(a4, 16); a5 += __shfl_xor(a5, 16);
    a6 += __shfl_xor(a6, 16); a7 += __shfl_xor(a7, 16);
    a0 += __shfl_xor(a0, 32); a1 += __shfl_xor(a1, 32);
    a2 += __shfl_xor(a2, 32); a3 += __shfl_xor(a3, 32);
    a4 += __shfl_xor(a4, 32); a5 += __shfl_xor(a5, 32);
    a6 += __shfl_xor(a6, 32); a7 += __shfl_xor(a7, 32);

    if (s < 16) {
        float* op = out + (size_t)tree * DIM + cb;
        *(float4*)op       = make_float4(a0, a1, a2, a3);
        *(float4*)(op + 4) = make_float4(a4, a5, a6, a7);
    }
}

// Fallback: fp32-table fused gather (structure validated rounds 7-8) for
// tiny workspaces.
__global__ __launch_bounds__(256, 4) void fused_kernel(
        const int* __restrict__ tokens, const void* __restrict__ masks,
        const float* __restrict__ ts, const float* __restrict__ emb,
        float* __restrict__ out) {
    __shared__ ull l_pair[TPA][TOT];

    const int tid  = threadIdx.x;
    const int w    = tid >> 6;
    const int s    = tid & 63;
    const int tree = blockIdx.x * TPA + w;
    const size_t base = (size_t)tree * TOT;

    const int nTot = recursion_and_sort(tokens, masks, ts, l_pair, w, s, base);

    const int hi = (s >= 32) ? 1 : 0;
    const int cb = (s & 31) << 2;
    const ull* lp = &l_pair[w][0];
    float a0 = 0.0f, a1 = 0.0f, a2 = 0.0f, a3 = 0.0f;

    int j = 0;
    for (; j + 8 <= nTot; j += 8) {
        ull pr[4];
        #pragma unroll
        for (int k = 0; k < 4; ++k) pr[k] = lp[j + 2 * k + hi];
        float4 v[4];
        #pragma unroll
        for (int k = 0; k < 4; ++k)
            v[k] = *(const float4*)(emb + (size_t)(unsigned)pr[k] * DIM + cb);
        #pragma unroll
        for (int k = 0; k < 4; ++k) {
            float wt = __uint_as_float((unsigned)(pr[k] >> 32));
            a0 = fmaf(wt, v[k].x, a0); a1 = fmaf(wt, v[k].y, a1);
            a2 = fmaf(wt, v[k].z, a2); a3 = fmaf(wt, v[k].w, a3);
        }
    }
    for (; j + 2 <= nTot; j += 2) {
        ull pr = lp[j + hi];
        float wt = __uint_as_float((unsigned)(pr >> 32));
        const float4 v = *(const float4*)(emb + (size_t)(unsigned)pr * DIM + cb);
        a0 = fmaf(wt, v.x, a0); a1 = fmaf(wt, v.y, a1);
        a2 = fmaf(wt, v.z, a2); a3 = fmaf(wt, v.w, a3);
    }
    if (j < nTot) {
        ull pr = lp[j];
        float wt = hi ? 0.0f : __uint_as_float((unsigned)(pr >> 32));
        const float4 v = *(const float4*)(emb + (size_t)(unsigned)pr * DIM + cb);
        a0 = fmaf(wt, v.x, a0); a1 = fmaf(wt, v.y, a1);
        a2 = fmaf(wt, v.z, a2); a3 = fmaf(wt, v.w, a3);
    }

    a0 += __shfl_xor(a0, 32);
    a1 += __shfl_xor(a1, 32);
    a2 += __shfl_xor(a2, 32);
    a3 += __shfl_xor(a3, 32);

    if (s < 32) {
        float* op = out + (size_t)tree * DIM + cb;
        *(float4*)op = make_float4(a0, a1, a2, a3);
    }
}

extern "C" void kernel_launch(void* const* d_in, const int* in_sizes, int n_in,
                              void* d_out, int out_size, void* d_ws, size_t ws_size,
                              hipStream_t stream) {
    const int*   tokens = (const int*)d_in[0];
    const void*  masks  = d_in[1];
    const float* emb    = (const float*)d_in[2];
    const float* cw     = (const float*)d_in[3];
    float*       out    = (float*)d_out;

    // Workspace: ts f32 (120 KB, padded to 128 KB) + fp16 table (7.68 MB).
    const size_t o_ts  = 0;
    const size_t o_e16 = 128 * 1024;
    const size_t need  = o_e16 + (size_t)VOCAB * DIM * 2;

    float*  ts  = (float*)((char*)d_ws + o_ts);
    __half* e16 = (__half*)((char*)d_ws + o_e16);

    const bool fp16path = (ws_size >= need);
    int ts_blocks = (VOCAB * 64 + 255) / 256;   // one wave per vocab row
    tokscore_kernel<<<ts_blocks, 256, 0, stream>>>(
        emb, cw, ts, fp16path ? (__half2*)e16 : (__half2*)nullptr);

    if (fp16path) {
        fused16_kernel<<<NUM_TREES / TPA, 256, 0, stream>>>(tokens, masks, ts,
                                                            e16, out);
    } else {
        fused_kernel<<<NUM_TREES / TPA, 256, 0, stream>>>(tokens, masks, ts,
                                                          emb, out);
    }
}